// Round 5
// baseline (77.207 us; speedup 1.0000x reference)
//
#include <hip/hip_runtime.h>

// Cutout: out[b,c,y,x] = img[b,c,y,x] * keep(b,y,x)
// B=64, C=3, H=512, W=512, MAX_HOLES=5 (num_holes in [0,5))
//
// R4: batched streaming — each thread moves 8 float4s at stride 8192 within
// its plane (every access lane-contiguous, copy-benchmark shape). All 8 loads
// issued before masks/stores (MLP). Hole boxes in scalar regs (b uniform per
// block via blockIdx.y); mask loop statically unrolled over all 5 slots with
// inactive slots made empty (y2=0) so all register indices are compile-time.

#define BB 64
#define CC 3
#define HH 512
#define WW 512
#define KK 5
#define W4 (WW / 4)              // 128 float4 per row
#define PLANE4 (HH * W4)         // 65536 float4 per (b,c) plane
#define TPP 8192                 // threads per plane
#define ITER (PLANE4 / TPP)      // 8 float4 per thread

typedef float v4f __attribute__((ext_vector_type(4)));

__global__ __launch_bounds__(256) void cutout_kernel(
    const v4f* __restrict__ img,
    const int* __restrict__ num_holes,
    const int* __restrict__ ys,
    const int* __restrict__ xs,
    const int* __restrict__ hs,
    const int* __restrict__ ws,
    v4f* __restrict__ out)
{
    int plane = blockIdx.y;                      // b*3 + c, uniform
    int b     = plane / 3;                       // uniform
    int tid   = blockIdx.x * 256 + threadIdx.x;  // 0..8191 within plane

    // Clamped hole boxes -> scalar regs; inactive slots emptied (sy2=0).
    int n = num_holes[b];
    int sy1[KK], sy2[KK], sx1[KK], sx2[KK];
#pragma unroll
    for (int k = 0; k < KK; ++k) {
        int yc = ys[b * KK + k];
        int xc = xs[b * KK + k];
        int hh = hs[b * KK + k];
        int wv = ws[b * KK + k];
        sy1[k] = max(0, yc - hh / 2);
        sy2[k] = (k < n) ? min(HH, yc + hh / 2) : 0;  // empty when inactive
        sx1[k] = max(0, xc - wv / 2);
        sx2[k] = min(WW, xc + wv / 2);
    }

    size_t qbase = (size_t)plane * PLANE4 + (size_t)tid;

    // Issue all loads first (8 outstanding VMEM ops per thread).
    v4f v[ITER];
#pragma unroll
    for (int i = 0; i < ITER; ++i)
        v[i] = img[qbase + (size_t)(i * TPP)];

#pragma unroll
    for (int i = 0; i < ITER; ++i) {
        int pos = tid + i * TPP;
        int y   = pos >> 7;            // row
        int x0  = (pos & 127) << 2;    // first pixel x of quad
        float m0 = 1.0f, m1 = 1.0f, m2 = 1.0f, m3 = 1.0f;
#pragma unroll
        for (int k = 0; k < KK; ++k) {
            if (y >= sy1[k] && y < sy2[k]) {
                if ((x0 + 0) >= sx1[k] && (x0 + 0) < sx2[k]) m0 = 0.0f;
                if ((x0 + 1) >= sx1[k] && (x0 + 1) < sx2[k]) m1 = 0.0f;
                if ((x0 + 2) >= sx1[k] && (x0 + 2) < sx2[k]) m2 = 0.0f;
                if ((x0 + 3) >= sx1[k] && (x0 + 3) < sx2[k]) m3 = 0.0f;
            }
        }
        v4f t = v[i];
        t.x *= m0; t.y *= m1; t.z *= m2; t.w *= m3;
        out[qbase + (size_t)(i * TPP)] = t;
    }
}

extern "C" void kernel_launch(void* const* d_in, const int* in_sizes, int n_in,
                              void* d_out, int out_size, void* d_ws, size_t ws_size,
                              hipStream_t stream) {
    const v4f* img         = (const v4f*)d_in[0];
    const int* num_holes   = (const int*)d_in[1];
    const int* ys          = (const int*)d_in[2];
    const int* xs          = (const int*)d_in[3];
    const int* hs          = (const int*)d_in[4];
    const int* ws          = (const int*)d_in[5];
    v4f* out               = (v4f*)d_out;

    dim3 grid(TPP / 256, BB * CC);   // (32, 192) blocks of 256 threads
    cutout_kernel<<<grid, dim3(256), 0, stream>>>(img, num_holes, ys, xs, hs, ws, out);
}

// Round 6
// 68.135 us; speedup vs baseline: 1.1331x; 1.1331x over previous
//
#include <hip/hip_runtime.h>

// Cutout: out[b,c,y,x] = img[b,c,y,x] * keep(b,y,x)
// B=64, C=3, H=512, W=512, MAX_HOLES=5 (num_holes in [0,5))
//
// R5: exactly R3's copy-shaped access (one float4 per thread, lane-contiguous,
// plane-linear sweep) + non-temporal load/store hints (pure stream, no reuse;
// keep the 256MB L3 from churning on a 403MB two-way stream).

#define BB 64
#define CC 3
#define HH 512
#define WW 512
#define KK 5
#define W4 (WW / 4)              // 128 float4 per row
#define PLANE4 (HH * W4)         // 65536 float4 per (b,c) plane

typedef float v4f __attribute__((ext_vector_type(4)));

__global__ __launch_bounds__(256) void cutout_kernel(
    const v4f* __restrict__ img,
    const int* __restrict__ num_holes,
    const int* __restrict__ ys,
    const int* __restrict__ xs,
    const int* __restrict__ hs,
    const int* __restrict__ ws,
    v4f* __restrict__ out)
{
    int plane = blockIdx.y;                       // b*3 + c, 0..191 (uniform)
    int b     = plane / 3;                        // uniform scalar divide
    int pos   = blockIdx.x * 256 + threadIdx.x;   // 0..65535 within plane
    int y     = pos >> 7;                         // row
    int x0    = (pos & 127) << 2;                 // first pixel x of quad

    float m0 = 1.0f, m1 = 1.0f, m2 = 1.0f, m3 = 1.0f;

    int n = num_holes[b];                         // scalar load, uniform
    for (int k = 0; k < n; ++k) {                 // uniform loop, n <= 4
        int yc = ys[b * KK + k];
        int xc = xs[b * KK + k];
        int hh = hs[b * KK + k];
        int wv = ws[b * KK + k];
        int y1 = max(0, yc - hh / 2);
        int y2 = min(HH, yc + hh / 2);
        int x1 = max(0, xc - wv / 2);
        int x2 = min(WW, xc + wv / 2);
        bool iny = (y >= y1) & (y < y2);
        if (iny) {
            if ((x0 + 0) >= x1 && (x0 + 0) < x2) m0 = 0.0f;
            if ((x0 + 1) >= x1 && (x0 + 1) < x2) m1 = 0.0f;
            if ((x0 + 2) >= x1 && (x0 + 2) < x2) m2 = 0.0f;
            if ((x0 + 3) >= x1 && (x0 + 3) < x2) m3 = 0.0f;
        }
    }

    size_t q = (size_t)plane * PLANE4 + (size_t)pos;
    v4f v = __builtin_nontemporal_load(&img[q]);
    v.x *= m0; v.y *= m1; v.z *= m2; v.w *= m3;
    __builtin_nontemporal_store(v, &out[q]);
}

extern "C" void kernel_launch(void* const* d_in, const int* in_sizes, int n_in,
                              void* d_out, int out_size, void* d_ws, size_t ws_size,
                              hipStream_t stream) {
    const v4f* img         = (const v4f*)d_in[0];
    const int* num_holes   = (const int*)d_in[1];
    const int* ys          = (const int*)d_in[2];
    const int* xs          = (const int*)d_in[3];
    const int* hs          = (const int*)d_in[4];
    const int* ws          = (const int*)d_in[5];
    v4f* out               = (v4f*)d_out;

    dim3 grid(PLANE4 / 256, BB * CC);   // (256, 192) blocks of 256 threads
    cutout_kernel<<<grid, dim3(256), 0, stream>>>(img, num_holes, ys, xs, hs, ws, out);
}